// Round 7
// baseline (595.938 us; speedup 1.0000x reference)
//
#include <hip/hip_runtime.h>

#define F_IN 128
#define HID  16
#define NEG  0.2f
#define WCOL 52    // 49 fused output cols (16+16+16+1) padded to float4 multiple
#define CCH  256   // edge chunks for bucket sort
#define BW   256   // nodes per dst-bucket (bucket = dst >> 8)

// ============================ CSR build: two-level bucket counting sort =====
// No global atomics anywhere (the round-3 profile showed each global atomic
// costs ~32B of HBM write-back: 3.2M atomics == ~100MB == ~128us).

// Pass A: per-chunk LDS histogram over dst-buckets -> countsT[b*CCH + c]
__global__ void __launch_bounds__(256) bucket_count_k(
    const int* __restrict__ ei, int E, int n, int nb, int* __restrict__ countsT)
{
    __shared__ int hist[512];
    int c = blockIdx.x;
    int Et = E + n;
    int per = (Et + CCH - 1) / CCH;
    int j0 = c * per, j1 = (j0 + per < Et) ? j0 + per : Et;
    for (int t = threadIdx.x; t < nb; t += 256) hist[t] = 0;
    __syncthreads();
    for (int j = j0 + threadIdx.x; j < j1; j += 256) {
        int d = (j < E) ? ei[E + j] : (j - E);   // coalesced dst read
        atomicAdd(&hist[d >> 8], 1);             // LDS atomic
    }
    __syncthreads();
    for (int t = threadIdx.x; t < nb; t += 256) countsT[t * CCH + c] = hist[t];
}

// Per-bucket exclusive scan over its CCH chunk counts (in place) + totals
__global__ void __launch_bounds__(CCH) chunk_scan_k(
    int* __restrict__ countsT, int* __restrict__ btotal)
{
    __shared__ int sh[CCH];
    int b = blockIdx.x;
    int v = countsT[b * CCH + threadIdx.x];
    sh[threadIdx.x] = v;
    __syncthreads();
    for (int off = 1; off < CCH; off <<= 1) {
        int t = (threadIdx.x >= (unsigned)off) ? sh[threadIdx.x - off] : 0;
        __syncthreads();
        sh[threadIdx.x] += t;
        __syncthreads();
    }
    countsT[b * CCH + threadIdx.x] = sh[threadIdx.x] - v;   // exclusive
    if (threadIdx.x == CCH - 1) btotal[b] = sh[threadIdx.x];
}

// Exclusive scan of bucket totals -> bbase[0..nb], also row_ptr[n] = Etot
__global__ void bucket_base_k(const int* __restrict__ btotal,
                              int* __restrict__ bbase, int nb,
                              int* __restrict__ row_ptr, int n)
{
    __shared__ int sh[512];
    int v = (threadIdx.x < (unsigned)nb) ? btotal[threadIdx.x] : 0;
    sh[threadIdx.x] = v;
    __syncthreads();
    for (int off = 1; off < 512; off <<= 1) {
        int t = (threadIdx.x >= (unsigned)off) ? sh[threadIdx.x - off] : 0;
        __syncthreads();
        sh[threadIdx.x] += t;
        __syncthreads();
    }
    if (threadIdx.x < (unsigned)nb) bbase[threadIdx.x] = sh[threadIdx.x] - v;
    if (threadIdx.x == (unsigned)(nb - 1)) {
        bbase[nb] = sh[threadIdx.x];
        row_ptr[n] = sh[threadIdx.x];
    }
}

// Pass B: scatter edges into bucket-sorted ebuf via LDS cursors (disjoint
// (bucket,chunk) ranges -> no races, ~264B contiguous runs -> no write blowup)
__global__ void __launch_bounds__(256) bucket_scatter_k(
    const int* __restrict__ ei, int E, int n, int nb,
    const int* __restrict__ countsT, const int* __restrict__ bbase,
    int2* __restrict__ ebuf)
{
    __shared__ int cur[512];
    int c = blockIdx.x;
    int Et = E + n;
    int per = (Et + CCH - 1) / CCH;
    int j0 = c * per, j1 = (j0 + per < Et) ? j0 + per : Et;
    for (int t = threadIdx.x; t < nb; t += 256)
        cur[t] = bbase[t] + countsT[t * CCH + c];
    __syncthreads();
    for (int j = j0 + threadIdx.x; j < j1; j += 256) {
        int s, d;
        if (j < E) { s = ei[j]; d = ei[E + j]; }
        else       { s = d = j - E; }            // self loops
        int pos = atomicAdd(&cur[d >> 8], 1);    // LDS atomic
        ebuf[pos] = make_int2(s, d);
    }
}

// Level 2: one block per bucket -> per-node degree (LDS), scan (LDS),
// row_ptr + rank-scatter col. All writes land in the bucket's L2 window.
__global__ void __launch_bounds__(256) bucket_csr_k(
    const int2* __restrict__ ebuf, const int* __restrict__ bbase,
    int* __restrict__ row_ptr, int* __restrict__ col, int n)
{
    __shared__ int deg[256];
    __shared__ int cur[256];
    int b = blockIdx.x;
    int e0 = bbase[b], e1 = bbase[b + 1];
    int n0 = b << 8;
    deg[threadIdx.x] = 0;
    __syncthreads();
    for (int j = e0 + threadIdx.x; j < e1; j += 256)
        atomicAdd(&deg[ebuf[j].y & 255], 1);     // LDS atomic
    __syncthreads();
    int v = deg[threadIdx.x];
    for (int off = 1; off < 256; off <<= 1) {
        int t = (threadIdx.x >= (unsigned)off) ? deg[threadIdx.x - off] : 0;
        __syncthreads();
        deg[threadIdx.x] += t;
        __syncthreads();
    }
    int excl = e0 + deg[threadIdx.x] - v;        // exclusive global offset
    int node = n0 + threadIdx.x;
    if (node < n) row_ptr[node] = excl;
    cur[threadIdx.x] = excl;
    __syncthreads();
    for (int j = e0 + threadIdx.x; j < e1; j += 256) {
        int2 e = ebuf[j];
        int pos = atomicAdd(&cur[e.y & 255], 1); // LDS atomic
        col[pos] = e.x;
    }
}

// ------------------------------------------------------------------ pre-pass
// acc[0:16)  = x @ W1            -> h (layer 1) + ss1/sd1
// acc[16:32) = x @ W2[16:144]    -> p2
// acc[32:48) = x @ W3[16:144]    -> p3
// acc[48]    = x @ W4[16:144]    -> p4
__global__ void __launch_bounds__(256) prep_k(
    const float* __restrict__ x,
    const float* __restrict__ W1, const float* __restrict__ as1,
    const float* __restrict__ ad1,
    const float* __restrict__ W2, const float* __restrict__ W3,
    const float* __restrict__ W4,
    float* __restrict__ h, float* __restrict__ ss, float* __restrict__ sd,
    float* __restrict__ p2, float* __restrict__ p3, float* __restrict__ p4,
    int n)
{
    __shared__ float WL[F_IN * WCOL];
    __shared__ float asl[16], adl[16];
    for (int idx = threadIdx.x; idx < F_IN * WCOL; idx += 256) {
        int f = idx / WCOL, o = idx - f * WCOL;
        float v = 0.f;
        if (o < 16)       v = W1[f * 16 + o];
        else if (o < 32)  v = W2[(HID + f) * 16 + (o - 16)];
        else if (o < 48)  v = W3[(HID + f) * 16 + (o - 32)];
        else if (o == 48) v = W4[HID + f];
        WL[idx] = v;
    }
    if (threadIdx.x < 16) {
        asl[threadIdx.x] = as1[threadIdx.x];
        adl[threadIdx.x] = ad1[threadIdx.x];
    }
    __syncthreads();
    int i = blockIdx.x * 256 + threadIdx.x;
    if (i >= n) return;

    float4 acc[13];
#pragma unroll
    for (int k = 0; k < 13; k++) acc[k] = make_float4(0.f, 0.f, 0.f, 0.f);

    const float4* xp = (const float4*)(x + (size_t)i * F_IN);
#pragma unroll 4
    for (int ff = 0; ff < F_IN / 4; ff++) {
        float4 v = xp[ff];
        float vs[4] = {v.x, v.y, v.z, v.w};
#pragma unroll
        for (int e = 0; e < 4; e++) {
            // uniform LDS address across the wave -> broadcast read
            const float4* w4 = (const float4*)(WL + (ff * 4 + e) * WCOL);
            float s = vs[e];
#pragma unroll
            for (int k = 0; k < 13; k++) {
                float4 w = w4[k];
                acc[k].x += s * w.x; acc[k].y += s * w.y;
                acc[k].z += s * w.z; acc[k].w += s * w.w;
            }
        }
    }

    float hl[16] = {acc[0].x, acc[0].y, acc[0].z, acc[0].w,
                    acc[1].x, acc[1].y, acc[1].z, acc[1].w,
                    acc[2].x, acc[2].y, acc[2].z, acc[2].w,
                    acc[3].x, acc[3].y, acc[3].z, acc[3].w};
    float s1 = 0.f, s2 = 0.f;
#pragma unroll
    for (int o = 0; o < 16; o++) { s1 += hl[o] * asl[o]; s2 += hl[o] * adl[o]; }

    float4* hp = (float4*)(h + (size_t)i * 16);
    hp[0] = acc[0]; hp[1] = acc[1]; hp[2] = acc[2]; hp[3] = acc[3];
    ss[i] = s1; sd[i] = s2;
    float4* p2p = (float4*)(p2 + (size_t)i * 16);
    p2p[0] = acc[4]; p2p[1] = acc[5]; p2p[2] = acc[6]; p2p[3] = acc[7];
    float4* p3p = (float4*)(p3 + (size_t)i * 16);
    p3p[0] = acc[8]; p3p[1] = acc[9]; p3p[2] = acc[10]; p3p[3] = acc[11];
    p4[i] = acc[12].x;
}

// --------------------------------------------- small per-layer transform 2/3
__global__ void __launch_bounds__(256) gemm_top_k(
    const float* __restrict__ xa, const float* __restrict__ p,
    const float* __restrict__ Wt,
    const float* __restrict__ as_, const float* __restrict__ ad_,
    float* __restrict__ h, float* __restrict__ ss, float* __restrict__ sd,
    int n)
{
    __shared__ float WL[16 * 16];
    __shared__ float asl[16], adl[16];
    if (threadIdx.x < 256) WL[threadIdx.x] = Wt[threadIdx.x];
    if (threadIdx.x < 16) {
        asl[threadIdx.x] = as_[threadIdx.x];
        adl[threadIdx.x] = ad_[threadIdx.x];
    }
    __syncthreads();
    int i = blockIdx.x * 256 + threadIdx.x;
    if (i >= n) return;

    const float4* pp = (const float4*)(p + (size_t)i * 16);
    float4 acc[4] = {pp[0], pp[1], pp[2], pp[3]};

    const float4* xr = (const float4*)(xa + (size_t)i * 16);
    float4 xv0 = xr[0], xv1 = xr[1], xv2 = xr[2], xv3 = xr[3];
    float xs[16] = {xv0.x, xv0.y, xv0.z, xv0.w, xv1.x, xv1.y, xv1.z, xv1.w,
                    xv2.x, xv2.y, xv2.z, xv2.w, xv3.x, xv3.y, xv3.z, xv3.w};
#pragma unroll
    for (int f = 0; f < 16; f++) {
        const float4* w4 = (const float4*)(WL + f * 16);   // broadcast
        float s = xs[f];
#pragma unroll
        for (int k = 0; k < 4; k++) {
            float4 w = w4[k];
            acc[k].x += s * w.x; acc[k].y += s * w.y;
            acc[k].z += s * w.z; acc[k].w += s * w.w;
        }
    }
    float hl[16] = {acc[0].x, acc[0].y, acc[0].z, acc[0].w,
                    acc[1].x, acc[1].y, acc[1].z, acc[1].w,
                    acc[2].x, acc[2].y, acc[2].z, acc[2].w,
                    acc[3].x, acc[3].y, acc[3].z, acc[3].w};
    float s1 = 0.f, s2 = 0.f;
#pragma unroll
    for (int o = 0; o < 16; o++) { s1 += hl[o] * asl[o]; s2 += hl[o] * adl[o]; }
    float4* hp = (float4*)(h + (size_t)i * 16);
    hp[0] = acc[0]; hp[1] = acc[1]; hp[2] = acc[2]; hp[3] = acc[3];
    ss[i] = s1; sd[i] = s2;
}

// layer-4 transform: h1 = xa @ W4[0:16] + p4
__global__ void __launch_bounds__(256) gemm1b_k(
    const float* __restrict__ xa, const float* __restrict__ p4,
    const float* __restrict__ W4, float* __restrict__ h1, int n)
{
    __shared__ float WL[16];
    if (threadIdx.x < 16) WL[threadIdx.x] = W4[threadIdx.x];
    __syncthreads();
    int i = blockIdx.x * 256 + threadIdx.x;
    if (i >= n) return;
    float a = p4[i];
    const float* xr = xa + (size_t)i * 16;
#pragma unroll
    for (int f = 0; f < 16; f++) a += xr[f] * WL[f];
    h1[i] = a;
}

// ---------------------------------- segment softmax + aggregate + bias + relu
// 4 lanes per node; lane g handles feature-quad g. SRC-BLOCKED 2-pass gather:
// pass p touches only h rows with src in [p*half, (p+1)*half) -> live gather
// window 3.2MB fits the 4MB per-XCD L2, so each h line is fetched once per
// XCD instead of once per edge (R6 profile: FETCH 184MB ~= E*64B, all-miss).
// Exact same per-destination sums up to fp reordering.
__global__ void __launch_bounds__(256) agg16_k(
    const int* __restrict__ row_ptr, const int* __restrict__ col,
    const float* __restrict__ h, const float* __restrict__ ss,
    const float* __restrict__ sd, const float* __restrict__ b,
    float* __restrict__ out, int n)
{
    int t = blockIdx.x * 256 + threadIdx.x;
    int i = t >> 2;
    int g = t & 3;
    if (i >= n) return;
    int st = row_ptr[i], en = row_ptr[i + 1];
    float sdv = sd[i];
    float4 bv = ((const float4*)b)[g];
    int half_n = n >> 1;

    float denom = 0.f;
    float4 acc = make_float4(0.f, 0.f, 0.f, 0.f);
#pragma unroll
    for (int p = 0; p < 2; p++) {
        for (int j = st; j < en; j++) {
            int s = col[j];
            if ((p == 0) ? (s >= half_n) : (s < half_n)) continue;
            float e = ss[s] + sdv;
            e = (e > 0.f) ? e : NEG * e;
            float w = __expf(e);
            denom += w;
            float4 hv = ((const float4*)(h + (size_t)s * 16))[g];
            acc.x += w * hv.x; acc.y += w * hv.y;
            acc.z += w * hv.z; acc.w += w * hv.w;
        }
    }
    float inv = 1.f / denom;
    float4 r;
    r.x = acc.x * inv + bv.x; r.x = (r.x > 0.f) ? r.x : 0.f;
    r.y = acc.y * inv + bv.y; r.y = (r.y > 0.f) ? r.y : 0.f;
    r.z = acc.z * inv + bv.z; r.z = (r.z > 0.f) ? r.z : 0.f;
    r.w = acc.w * inv + bv.w; r.w = (r.w > 0.f) ? r.w : 0.f;
    ((float4*)(out + (size_t)i * 16))[g] = r;
}

__global__ void __launch_bounds__(256) agg1_k(
    const int* __restrict__ row_ptr, const int* __restrict__ col,
    const float* __restrict__ h1, const float* __restrict__ as4,
    const float* __restrict__ ad4, const float* __restrict__ b4,
    float* __restrict__ px, int n)
{
    int i = blockIdx.x * 256 + threadIdx.x;
    if (i >= n) return;
    float A = as4[0], D = ad4[0], B = b4[0];
    int st = row_ptr[i], en = row_ptr[i + 1];
    float sdv = h1[i] * D;

    float denom = 0.f, acc = 0.f;
    for (int j = st; j < en; j++) {
        float hv = h1[col[j]];
        float e = A * hv + sdv;
        e = (e > 0.f) ? e : NEG * e;
        float w = __expf(e);
        denom += w;
        acc += w * hv;
    }
    float val = acc / denom + B;
    px[i] = (val > 0.f) ? val : 0.f;
}

// ------------------------------------------------------------------ readout
__global__ void __launch_bounds__(256) readout_k(const float* __restrict__ xa3,
                                                 const float* __restrict__ fcw1,
                                                 const float* __restrict__ fcb1,
                                                 const float* __restrict__ fcw2,
                                                 const float* __restrict__ fcb2,
                                                 float* __restrict__ vx,
                                                 int nodes_per_graph) {
    __shared__ float red[256 * 17];
    int g = blockIdx.x;
    float p[16];
#pragma unroll
    for (int k = 0; k < 16; k++) p[k] = 0.f;
    for (int i = threadIdx.x; i < nodes_per_graph; i += 256) {
        const float* r = xa3 + ((size_t)g * nodes_per_graph + i) * 16;
#pragma unroll
        for (int k = 0; k < 16; k++) p[k] += r[k];
    }
#pragma unroll
    for (int k = 0; k < 16; k++) red[threadIdx.x * 17 + k] = p[k];
    __syncthreads();
    for (int s = 128; s > 0; s >>= 1) {
        if (threadIdx.x < (unsigned)s) {
#pragma unroll
            for (int k = 0; k < 16; k++)
                red[threadIdx.x * 17 + k] += red[(threadIdx.x + s) * 17 + k];
        }
        __syncthreads();
    }
    if (threadIdx.x == 0) {
        float inv = 1.f / (float)nodes_per_graph;
        float v[16];
#pragma unroll
        for (int k = 0; k < 16; k++) v[k] = red[k] * inv;
        float o = fcb2[0];
#pragma unroll
        for (int j = 0; j < 16; j++) {
            float hsum = fcb1[j];
#pragma unroll
            for (int k = 0; k < 16; k++) hsum += v[k] * fcw1[k * 16 + j];
            hsum = (hsum > 0.f) ? hsum : 0.f;
            o += hsum * fcw2[j];
        }
        vx[g] = o;
    }
}

// ------------------------------------------------------------------ launch
extern "C" void kernel_launch(void* const* d_in, const int* in_sizes, int n_in,
                              void* d_out, int out_size, void* d_ws, size_t ws_size,
                              hipStream_t stream) {
    const float* x   = (const float*)d_in[0];
    const int*   ei  = (const int*)  d_in[1];
    const float* W1  = (const float*)d_in[3];
    const float* as1 = (const float*)d_in[4];
    const float* ad1 = (const float*)d_in[5];
    const float* b1  = (const float*)d_in[6];
    const float* W2  = (const float*)d_in[7];
    const float* as2 = (const float*)d_in[8];
    const float* ad2 = (const float*)d_in[9];
    const float* b2  = (const float*)d_in[10];
    const float* W3  = (const float*)d_in[11];
    const float* as3 = (const float*)d_in[12];
    const float* ad3 = (const float*)d_in[13];
    const float* b3  = (const float*)d_in[14];
    const float* W4  = (const float*)d_in[15];
    const float* as4 = (const float*)d_in[16];
    const float* ad4 = (const float*)d_in[17];
    const float* b4  = (const float*)d_in[18];
    const float* fcw1= (const float*)d_in[19];
    const float* fcb1= (const float*)d_in[20];
    const float* fcw2= (const float*)d_in[21];
    const float* fcb2= (const float*)d_in[22];

    const int N = in_sizes[0] / F_IN;
    const int E = in_sizes[1] / 2;
    const int Etot = E + N;
    const int NB = (N + BW - 1) / BW;     // dst buckets (<=512 for N<=131072)

    // workspace carve (all arrays 256B-aligned)
    char* p = (char*)d_ws;
    auto carve = [&](size_t bytes) -> void* {
        void* r = (void*)p;
        p += (bytes + 255) & ~(size_t)255;
        return r;
    };
    int*   row_ptr = (int*)carve((size_t)(N + 1) * 4);
    int*   col     = (int*)carve((size_t)Etot * 4);
    int*   countsT = (int*)carve((size_t)NB * CCH * 4);
    int*   btotal  = (int*)carve((size_t)NB * 4);
    int*   bbase   = (int*)carve((size_t)(NB + 1) * 4);
    int2*  ebuf    = (int2*)carve((size_t)Etot * 8);
    float* h       = (float*)carve((size_t)N * 16 * 4);
    float* ss      = (float*)carve((size_t)N * 4);
    float* sd      = (float*)carve((size_t)N * 4);
    float* h1      = (float*)carve((size_t)N * 4);
    float* xa_a    = (float*)carve((size_t)N * 16 * 4);
    float* xa_b    = (float*)carve((size_t)N * 16 * 4);
    float* p2      = (float*)carve((size_t)N * 16 * 4);
    float* p3      = (float*)carve((size_t)N * 16 * 4);
    float* p4      = (float*)carve((size_t)N * 4);

    const int gN  = (N + 255) / 256;
    const int g4N = (N * 4 + 255) / 256;

    // ---- CSR build: bucket counting sort, zero global atomics
    bucket_count_k  <<<CCH, 256, 0, stream>>>(ei, E, N, NB, countsT);
    chunk_scan_k    <<<NB,  CCH, 0, stream>>>(countsT, btotal);
    bucket_base_k   <<<1,   512, 0, stream>>>(btotal, bbase, NB, row_ptr, N);
    bucket_scatter_k<<<CCH, 256, 0, stream>>>(ei, E, N, NB, countsT, bbase, ebuf);
    bucket_csr_k    <<<NB,  256, 0, stream>>>(ebuf, bbase, row_ptr, col, N);

    float* px = (float*)d_out;          // [N] = [100 graphs x 1000]
    float* vx = px + (size_t)N;         // [n_graphs]

    // ---- fused pre-pass: x read ONCE -> layer1 h/ss/sd + p2/p3/p4
    prep_k<<<gN, 256, 0, stream>>>(x, W1, as1, ad1, W2, W3, W4,
                                   h, ss, sd, p2, p3, p4, N);
    // ---- layer 1 aggregate -> xa_a
    agg16_k<<<g4N, 256, 0, stream>>>(row_ptr, col, h, ss, sd, b1, xa_a, N);
    // ---- layer 2
    gemm_top_k<<<gN, 256, 0, stream>>>(xa_a, p2, W2, as2, ad2, h, ss, sd, N);
    agg16_k<<<g4N, 256, 0, stream>>>(row_ptr, col, h, ss, sd, b2, xa_b, N);
    // ---- layer 3 (output xa_a = xa3 feeds readout)
    gemm_top_k<<<gN, 256, 0, stream>>>(xa_b, p3, W3, as3, ad3, h, ss, sd, N);
    agg16_k<<<g4N, 256, 0, stream>>>(row_ptr, col, h, ss, sd, b3, xa_a, N);
    // ---- layer 4 (out dim 1)
    gemm1b_k<<<gN, 256, 0, stream>>>(xa_a, p4, W4, h1, N);
    agg1_k<<<gN, 256, 0, stream>>>(row_ptr, col, h1, as4, ad4, b4, px, N);

    // ---- readout
    const int npg = 1000;
    const int ngraph = N / npg;
    readout_k<<<ngraph, 256, 0, stream>>>(xa_a, fcw1, fcb1, fcw2, fcb2, vx, npg);
}

// Round 10
// 497.339 us; speedup vs baseline: 1.1983x; 1.1983x over previous
//
#include <hip/hip_runtime.h>

#define F_IN 128
#define HID  16
#define NEG  0.2f
#define WCOL 52    // 49 fused output cols (16+16+16+1) padded to float4 multiple
#define CCH  256   // edge chunks for bucket sort
#define BW   256   // nodes per dst-bucket (bucket = dst >> 8)

// ============================ CSR build: two-level bucket counting sort =====
// No global atomics anywhere (the round-3 profile showed each global atomic
// costs ~32B of HBM write-back: 3.2M atomics == ~100MB == ~128us).

// Pass A: per-chunk LDS histogram over dst-buckets -> countsT[b*CCH + c]
__global__ void __launch_bounds__(256) bucket_count_k(
    const int* __restrict__ ei, int E, int n, int nb, int* __restrict__ countsT)
{
    __shared__ int hist[512];
    int c = blockIdx.x;
    int Et = E + n;
    int per = (Et + CCH - 1) / CCH;
    int j0 = c * per, j1 = (j0 + per < Et) ? j0 + per : Et;
    for (int t = threadIdx.x; t < nb; t += 256) hist[t] = 0;
    __syncthreads();
    for (int j = j0 + threadIdx.x; j < j1; j += 256) {
        int d = (j < E) ? ei[E + j] : (j - E);   // coalesced dst read
        atomicAdd(&hist[d >> 8], 1);             // LDS atomic
    }
    __syncthreads();
    for (int t = threadIdx.x; t < nb; t += 256) countsT[t * CCH + c] = hist[t];
}

// Per-bucket exclusive scan over its CCH chunk counts (in place) + totals
__global__ void __launch_bounds__(CCH) chunk_scan_k(
    int* __restrict__ countsT, int* __restrict__ btotal)
{
    __shared__ int sh[CCH];
    int b = blockIdx.x;
    int v = countsT[b * CCH + threadIdx.x];
    sh[threadIdx.x] = v;
    __syncthreads();
    for (int off = 1; off < CCH; off <<= 1) {
        int t = (threadIdx.x >= (unsigned)off) ? sh[threadIdx.x - off] : 0;
        __syncthreads();
        sh[threadIdx.x] += t;
        __syncthreads();
    }
    countsT[b * CCH + threadIdx.x] = sh[threadIdx.x] - v;   // exclusive
    if (threadIdx.x == CCH - 1) btotal[b] = sh[threadIdx.x];
}

// Exclusive scan of bucket totals -> bbase[0..nb], also row_ptr[n] = Etot
__global__ void bucket_base_k(const int* __restrict__ btotal,
                              int* __restrict__ bbase, int nb,
                              int* __restrict__ row_ptr, int n)
{
    __shared__ int sh[512];
    int v = (threadIdx.x < (unsigned)nb) ? btotal[threadIdx.x] : 0;
    sh[threadIdx.x] = v;
    __syncthreads();
    for (int off = 1; off < 512; off <<= 1) {
        int t = (threadIdx.x >= (unsigned)off) ? sh[threadIdx.x - off] : 0;
        __syncthreads();
        sh[threadIdx.x] += t;
        __syncthreads();
    }
    if (threadIdx.x < (unsigned)nb) bbase[threadIdx.x] = sh[threadIdx.x] - v;
    if (threadIdx.x == (unsigned)(nb - 1)) {
        bbase[nb] = sh[threadIdx.x];
        row_ptr[n] = sh[threadIdx.x];
    }
}

// Pass B: scatter edges into bucket-sorted ebuf via LDS cursors (disjoint
// (bucket,chunk) ranges -> no races, ~264B contiguous runs -> no write blowup)
__global__ void __launch_bounds__(256) bucket_scatter_k(
    const int* __restrict__ ei, int E, int n, int nb,
    const int* __restrict__ countsT, const int* __restrict__ bbase,
    int2* __restrict__ ebuf)
{
    __shared__ int cur[512];
    int c = blockIdx.x;
    int Et = E + n;
    int per = (Et + CCH - 1) / CCH;
    int j0 = c * per, j1 = (j0 + per < Et) ? j0 + per : Et;
    for (int t = threadIdx.x; t < nb; t += 256)
        cur[t] = bbase[t] + countsT[t * CCH + c];
    __syncthreads();
    for (int j = j0 + threadIdx.x; j < j1; j += 256) {
        int s, d;
        if (j < E) { s = ei[j]; d = ei[E + j]; }
        else       { s = d = j - E; }            // self loops
        int pos = atomicAdd(&cur[d >> 8], 1);    // LDS atomic
        ebuf[pos] = make_int2(s, d);
    }
}

// Level 2: one block per bucket -> per-node degree (LDS), scan (LDS),
// row_ptr + rank-scatter col. All writes land in the bucket's L2 window.
__global__ void __launch_bounds__(256) bucket_csr_k(
    const int2* __restrict__ ebuf, const int* __restrict__ bbase,
    int* __restrict__ row_ptr, int* __restrict__ col, int n)
{
    __shared__ int deg[256];
    __shared__ int cur[256];
    int b = blockIdx.x;
    int e0 = bbase[b], e1 = bbase[b + 1];
    int n0 = b << 8;
    deg[threadIdx.x] = 0;
    __syncthreads();
    for (int j = e0 + threadIdx.x; j < e1; j += 256)
        atomicAdd(&deg[ebuf[j].y & 255], 1);     // LDS atomic
    __syncthreads();
    int v = deg[threadIdx.x];
    for (int off = 1; off < 256; off <<= 1) {
        int t = (threadIdx.x >= (unsigned)off) ? deg[threadIdx.x - off] : 0;
        __syncthreads();
        deg[threadIdx.x] += t;
        __syncthreads();
    }
    int excl = e0 + deg[threadIdx.x] - v;        // exclusive global offset
    int node = n0 + threadIdx.x;
    if (node < n) row_ptr[node] = excl;
    cur[threadIdx.x] = excl;
    __syncthreads();
    for (int j = e0 + threadIdx.x; j < e1; j += 256) {
        int2 e = ebuf[j];
        int pos = atomicAdd(&cur[e.y & 255], 1); // LDS atomic
        col[pos] = e.x;
    }
}

// ------------------------------------------------------------------ pre-pass
// acc[0:16)  = x @ W1            -> h (layer 1) + ss1/sd1
// acc[16:32) = x @ W2[16:144]    -> p2
// acc[32:48) = x @ W3[16:144]    -> p3
// acc[48]    = x @ W4[16:144]    -> p4
__global__ void __launch_bounds__(256) prep_k(
    const float* __restrict__ x,
    const float* __restrict__ W1, const float* __restrict__ as1,
    const float* __restrict__ ad1,
    const float* __restrict__ W2, const float* __restrict__ W3,
    const float* __restrict__ W4,
    float* __restrict__ h, float* __restrict__ ss, float* __restrict__ sd,
    float* __restrict__ p2, float* __restrict__ p3, float* __restrict__ p4,
    int n)
{
    __shared__ float WL[F_IN * WCOL];
    __shared__ float asl[16], adl[16];
    for (int idx = threadIdx.x; idx < F_IN * WCOL; idx += 256) {
        int f = idx / WCOL, o = idx - f * WCOL;
        float v = 0.f;
        if (o < 16)       v = W1[f * 16 + o];
        else if (o < 32)  v = W2[(HID + f) * 16 + (o - 16)];
        else if (o < 48)  v = W3[(HID + f) * 16 + (o - 32)];
        else if (o == 48) v = W4[HID + f];
        WL[idx] = v;
    }
    if (threadIdx.x < 16) {
        asl[threadIdx.x] = as1[threadIdx.x];
        adl[threadIdx.x] = ad1[threadIdx.x];
    }
    __syncthreads();
    int i = blockIdx.x * 256 + threadIdx.x;
    if (i >= n) return;

    float4 acc[13];
#pragma unroll
    for (int k = 0; k < 13; k++) acc[k] = make_float4(0.f, 0.f, 0.f, 0.f);

    const float4* xp = (const float4*)(x + (size_t)i * F_IN);
#pragma unroll 4
    for (int ff = 0; ff < F_IN / 4; ff++) {
        float4 v = xp[ff];
        float vs[4] = {v.x, v.y, v.z, v.w};
#pragma unroll
        for (int e = 0; e < 4; e++) {
            // uniform LDS address across the wave -> broadcast read
            const float4* w4 = (const float4*)(WL + (ff * 4 + e) * WCOL);
            float s = vs[e];
#pragma unroll
            for (int k = 0; k < 13; k++) {
                float4 w = w4[k];
                acc[k].x += s * w.x; acc[k].y += s * w.y;
                acc[k].z += s * w.z; acc[k].w += s * w.w;
            }
        }
    }

    float hl[16] = {acc[0].x, acc[0].y, acc[0].z, acc[0].w,
                    acc[1].x, acc[1].y, acc[1].z, acc[1].w,
                    acc[2].x, acc[2].y, acc[2].z, acc[2].w,
                    acc[3].x, acc[3].y, acc[3].z, acc[3].w};
    float s1 = 0.f, s2 = 0.f;
#pragma unroll
    for (int o = 0; o < 16; o++) { s1 += hl[o] * asl[o]; s2 += hl[o] * adl[o]; }

    float4* hp = (float4*)(h + (size_t)i * 16);
    hp[0] = acc[0]; hp[1] = acc[1]; hp[2] = acc[2]; hp[3] = acc[3];
    ss[i] = s1; sd[i] = s2;
    float4* p2p = (float4*)(p2 + (size_t)i * 16);
    p2p[0] = acc[4]; p2p[1] = acc[5]; p2p[2] = acc[6]; p2p[3] = acc[7];
    float4* p3p = (float4*)(p3 + (size_t)i * 16);
    p3p[0] = acc[8]; p3p[1] = acc[9]; p3p[2] = acc[10]; p3p[3] = acc[11];
    p4[i] = acc[12].x;
}

// --------------------------------------------- small per-layer transform 2/3
__global__ void __launch_bounds__(256) gemm_top_k(
    const float* __restrict__ xa, const float* __restrict__ p,
    const float* __restrict__ Wt,
    const float* __restrict__ as_, const float* __restrict__ ad_,
    float* __restrict__ h, float* __restrict__ ss, float* __restrict__ sd,
    int n)
{
    __shared__ float WL[16 * 16];
    __shared__ float asl[16], adl[16];
    if (threadIdx.x < 256) WL[threadIdx.x] = Wt[threadIdx.x];
    if (threadIdx.x < 16) {
        asl[threadIdx.x] = as_[threadIdx.x];
        adl[threadIdx.x] = ad_[threadIdx.x];
    }
    __syncthreads();
    int i = blockIdx.x * 256 + threadIdx.x;
    if (i >= n) return;

    const float4* pp = (const float4*)(p + (size_t)i * 16);
    float4 acc[4] = {pp[0], pp[1], pp[2], pp[3]};

    const float4* xr = (const float4*)(xa + (size_t)i * 16);
    float4 xv0 = xr[0], xv1 = xr[1], xv2 = xr[2], xv3 = xr[3];
    float xs[16] = {xv0.x, xv0.y, xv0.z, xv0.w, xv1.x, xv1.y, xv1.z, xv1.w,
                    xv2.x, xv2.y, xv2.z, xv2.w, xv3.x, xv3.y, xv3.z, xv3.w};
#pragma unroll
    for (int f = 0; f < 16; f++) {
        const float4* w4 = (const float4*)(WL + f * 16);   // broadcast
        float s = xs[f];
#pragma unroll
        for (int k = 0; k < 4; k++) {
            float4 w = w4[k];
            acc[k].x += s * w.x; acc[k].y += s * w.y;
            acc[k].z += s * w.z; acc[k].w += s * w.w;
        }
    }
    float hl[16] = {acc[0].x, acc[0].y, acc[0].z, acc[0].w,
                    acc[1].x, acc[1].y, acc[1].z, acc[1].w,
                    acc[2].x, acc[2].y, acc[2].z, acc[2].w,
                    acc[3].x, acc[3].y, acc[3].z, acc[3].w};
    float s1 = 0.f, s2 = 0.f;
#pragma unroll
    for (int o = 0; o < 16; o++) { s1 += hl[o] * asl[o]; s2 += hl[o] * adl[o]; }
    float4* hp = (float4*)(h + (size_t)i * 16);
    hp[0] = acc[0]; hp[1] = acc[1]; hp[2] = acc[2]; hp[3] = acc[3];
    ss[i] = s1; sd[i] = s2;
}

// layer-4 transform: h1 = xa @ W4[0:16] + p4
__global__ void __launch_bounds__(256) gemm1b_k(
    const float* __restrict__ xa, const float* __restrict__ p4,
    const float* __restrict__ W4, float* __restrict__ h1, int n)
{
    __shared__ float WL[16];
    if (threadIdx.x < 16) WL[threadIdx.x] = W4[threadIdx.x];
    __syncthreads();
    int i = blockIdx.x * 256 + threadIdx.x;
    if (i >= n) return;
    float a = p4[i];
    const float* xr = xa + (size_t)i * 16;
#pragma unroll
    for (int f = 0; f < 16; f++) a += xr[f] * WL[f];
    h1[i] = a;
}

// ---------------------------------- segment softmax + aggregate + bias + relu
// 4 lanes per node; lane g handles feature-quad g. Single pass (R7's 2-pass
// src-blocking REGRESSED: latency-bound, not traffic-bound). Edge loop
// unrolled x8 in three phases (col batch -> 8 indep ss gathers+exp -> 8 indep
// h gathers -> accumulate) to raise outstanding misses per wave from ~2 to ~8.
__global__ void __launch_bounds__(256) agg16_k(
    const int* __restrict__ row_ptr, const int* __restrict__ col,
    const float* __restrict__ h, const float* __restrict__ ss,
    const float* __restrict__ sd, const float* __restrict__ b,
    float* __restrict__ out, int n)
{
    int t = blockIdx.x * 256 + threadIdx.x;
    int i = t >> 2;
    int g = t & 3;
    if (i >= n) return;
    int st = row_ptr[i], en = row_ptr[i + 1];
    float sdv = sd[i];
    float4 bv = ((const float4*)b)[g];

    float denom = 0.f;
    float4 acc = make_float4(0.f, 0.f, 0.f, 0.f);

    int j = st;
    for (; j + 8 <= en; j += 8) {
        int s[8];
#pragma unroll
        for (int k = 0; k < 8; k++) s[k] = col[j + k];
        float w[8];
#pragma unroll
        for (int k = 0; k < 8; k++) {
            float e = ss[s[k]] + sdv;
            e = (e > 0.f) ? e : NEG * e;
            w[k] = __expf(e);
        }
        float4 hv[8];
#pragma unroll
        for (int k = 0; k < 8; k++)
            hv[k] = ((const float4*)(h + (size_t)s[k] * 16))[g];
#pragma unroll
        for (int k = 0; k < 8; k++) {
            denom += w[k];
            acc.x += w[k] * hv[k].x; acc.y += w[k] * hv[k].y;
            acc.z += w[k] * hv[k].z; acc.w += w[k] * hv[k].w;
        }
    }
    for (; j < en; j++) {
        int s = col[j];
        float e = ss[s] + sdv;
        e = (e > 0.f) ? e : NEG * e;
        float w = __expf(e);
        denom += w;
        float4 hv = ((const float4*)(h + (size_t)s * 16))[g];
        acc.x += w * hv.x; acc.y += w * hv.y;
        acc.z += w * hv.z; acc.w += w * hv.w;
    }

    float inv = 1.f / denom;
    float4 r;
    r.x = acc.x * inv + bv.x; r.x = (r.x > 0.f) ? r.x : 0.f;
    r.y = acc.y * inv + bv.y; r.y = (r.y > 0.f) ? r.y : 0.f;
    r.z = acc.z * inv + bv.z; r.z = (r.z > 0.f) ? r.z : 0.f;
    r.w = acc.w * inv + bv.w; r.w = (r.w > 0.f) ? r.w : 0.f;
    ((float4*)(out + (size_t)i * 16))[g] = r;
}

// same x8 phase-batched unroll as agg16_k (identical serial-chain structure;
// h1 is 400KB so gathers are L2-resident -> lower latency but same MLP logic)
__global__ void __launch_bounds__(256) agg1_k(
    const int* __restrict__ row_ptr, const int* __restrict__ col,
    const float* __restrict__ h1, const float* __restrict__ as4,
    const float* __restrict__ ad4, const float* __restrict__ b4,
    float* __restrict__ px, int n)
{
    int i = blockIdx.x * 256 + threadIdx.x;
    if (i >= n) return;
    float A = as4[0], D = ad4[0], B = b4[0];
    int st = row_ptr[i], en = row_ptr[i + 1];
    float sdv = h1[i] * D;

    float denom = 0.f, acc = 0.f;
    int j = st;
    for (; j + 8 <= en; j += 8) {
        int s[8];
#pragma unroll
        for (int k = 0; k < 8; k++) s[k] = col[j + k];
        float hv[8];
#pragma unroll
        for (int k = 0; k < 8; k++) hv[k] = h1[s[k]];
#pragma unroll
        for (int k = 0; k < 8; k++) {
            float e = A * hv[k] + sdv;
            e = (e > 0.f) ? e : NEG * e;
            float w = __expf(e);
            denom += w;
            acc += w * hv[k];
        }
    }
    for (; j < en; j++) {
        float hv = h1[col[j]];
        float e = A * hv + sdv;
        e = (e > 0.f) ? e : NEG * e;
        float w = __expf(e);
        denom += w;
        acc += w * hv;
    }
    float val = acc / denom + B;
    px[i] = (val > 0.f) ? val : 0.f;
}

// ------------------------------------------------------------------ readout
__global__ void __launch_bounds__(256) readout_k(const float* __restrict__ xa3,
                                                 const float* __restrict__ fcw1,
                                                 const float* __restrict__ fcb1,
                                                 const float* __restrict__ fcw2,
                                                 const float* __restrict__ fcb2,
                                                 float* __restrict__ vx,
                                                 int nodes_per_graph) {
    __shared__ float red[256 * 17];
    int g = blockIdx.x;
    float p[16];
#pragma unroll
    for (int k = 0; k < 16; k++) p[k] = 0.f;
    for (int i = threadIdx.x; i < nodes_per_graph; i += 256) {
        const float* r = xa3 + ((size_t)g * nodes_per_graph + i) * 16;
#pragma unroll
        for (int k = 0; k < 16; k++) p[k] += r[k];
    }
#pragma unroll
    for (int k = 0; k < 16; k++) red[threadIdx.x * 17 + k] = p[k];
    __syncthreads();
    for (int s = 128; s > 0; s >>= 1) {
        if (threadIdx.x < (unsigned)s) {
#pragma unroll
            for (int k = 0; k < 16; k++)
                red[threadIdx.x * 17 + k] += red[(threadIdx.x + s) * 17 + k];
        }
        __syncthreads();
    }
    if (threadIdx.x == 0) {
        float inv = 1.f / (float)nodes_per_graph;
        float v[16];
#pragma unroll
        for (int k = 0; k < 16; k++) v[k] = red[k] * inv;
        float o = fcb2[0];
#pragma unroll
        for (int j = 0; j < 16; j++) {
            float hsum = fcb1[j];
#pragma unroll
            for (int k = 0; k < 16; k++) hsum += v[k] * fcw1[k * 16 + j];
            hsum = (hsum > 0.f) ? hsum : 0.f;
            o += hsum * fcw2[j];
        }
        vx[g] = o;
    }
}

// ------------------------------------------------------------------ launch
extern "C" void kernel_launch(void* const* d_in, const int* in_sizes, int n_in,
                              void* d_out, int out_size, void* d_ws, size_t ws_size,
                              hipStream_t stream) {
    const float* x   = (const float*)d_in[0];
    const int*   ei  = (const int*)  d_in[1];
    const float* W1  = (const float*)d_in[3];
    const float* as1 = (const float*)d_in[4];
    const float* ad1 = (const float*)d_in[5];
    const float* b1  = (const float*)d_in[6];
    const float* W2  = (const float*)d_in[7];
    const float* as2 = (const float*)d_in[8];
    const float* ad2 = (const float*)d_in[9];
    const float* b2  = (const float*)d_in[10];
    const float* W3  = (const float*)d_in[11];
    const float* as3 = (const float*)d_in[12];
    const float* ad3 = (const float*)d_in[13];
    const float* b3  = (const float*)d_in[14];
    const float* W4  = (const float*)d_in[15];
    const float* as4 = (const float*)d_in[16];
    const float* ad4 = (const float*)d_in[17];
    const float* b4  = (const float*)d_in[18];
    const float* fcw1= (const float*)d_in[19];
    const float* fcb1= (const float*)d_in[20];
    const float* fcw2= (const float*)d_in[21];
    const float* fcb2= (const float*)d_in[22];

    const int N = in_sizes[0] / F_IN;
    const int E = in_sizes[1] / 2;
    const int Etot = E + N;
    const int NB = (N + BW - 1) / BW;     // dst buckets (<=512 for N<=131072)

    // workspace carve (all arrays 256B-aligned)
    char* p = (char*)d_ws;
    auto carve = [&](size_t bytes) -> void* {
        void* r = (void*)p;
        p += (bytes + 255) & ~(size_t)255;
        return r;
    };
    int*   row_ptr = (int*)carve((size_t)(N + 1) * 4);
    int*   col     = (int*)carve((size_t)Etot * 4);
    int*   countsT = (int*)carve((size_t)NB * CCH * 4);
    int*   btotal  = (int*)carve((size_t)NB * 4);
    int*   bbase   = (int*)carve((size_t)(NB + 1) * 4);
    int2*  ebuf    = (int2*)carve((size_t)Etot * 8);
    float* h       = (float*)carve((size_t)N * 16 * 4);
    float* ss      = (float*)carve((size_t)N * 4);
    float* sd      = (float*)carve((size_t)N * 4);
    float* h1      = (float*)carve((size_t)N * 4);
    float* xa_a    = (float*)carve((size_t)N * 16 * 4);
    float* xa_b    = (float*)carve((size_t)N * 16 * 4);
    float* p2      = (float*)carve((size_t)N * 16 * 4);
    float* p3      = (float*)carve((size_t)N * 16 * 4);
    float* p4      = (float*)carve((size_t)N * 4);

    const int gN  = (N + 255) / 256;
    const int g4N = (N * 4 + 255) / 256;

    // ---- CSR build: bucket counting sort, zero global atomics
    bucket_count_k  <<<CCH, 256, 0, stream>>>(ei, E, N, NB, countsT);
    chunk_scan_k    <<<NB,  CCH, 0, stream>>>(countsT, btotal);
    bucket_base_k   <<<1,   512, 0, stream>>>(btotal, bbase, NB, row_ptr, N);
    bucket_scatter_k<<<CCH, 256, 0, stream>>>(ei, E, N, NB, countsT, bbase, ebuf);
    bucket_csr_k    <<<NB,  256, 0, stream>>>(ebuf, bbase, row_ptr, col, N);

    float* px = (float*)d_out;          // [N] = [100 graphs x 1000]
    float* vx = px + (size_t)N;         // [n_graphs]

    // ---- fused pre-pass: x read ONCE -> layer1 h/ss/sd + p2/p3/p4
    prep_k<<<gN, 256, 0, stream>>>(x, W1, as1, ad1, W2, W3, W4,
                                   h, ss, sd, p2, p3, p4, N);
    // ---- layer 1 aggregate -> xa_a
    agg16_k<<<g4N, 256, 0, stream>>>(row_ptr, col, h, ss, sd, b1, xa_a, N);
    // ---- layer 2
    gemm_top_k<<<gN, 256, 0, stream>>>(xa_a, p2, W2, as2, ad2, h, ss, sd, N);
    agg16_k<<<g4N, 256, 0, stream>>>(row_ptr, col, h, ss, sd, b2, xa_b, N);
    // ---- layer 3 (output xa_a = xa3 feeds readout)
    gemm_top_k<<<gN, 256, 0, stream>>>(xa_b, p3, W3, as3, ad3, h, ss, sd, N);
    agg16_k<<<g4N, 256, 0, stream>>>(row_ptr, col, h, ss, sd, b3, xa_a, N);
    // ---- layer 4 (out dim 1)
    gemm1b_k<<<gN, 256, 0, stream>>>(xa_a, p4, W4, h1, N);
    agg1_k<<<gN, 256, 0, stream>>>(row_ptr, col, h1, as4, ad4, b4, px, N);

    // ---- readout
    const int npg = 1000;
    const int ngraph = N / npg;
    readout_k<<<ngraph, 256, 0, stream>>>(xa_a, fcw1, fcb1, fcw2, fcb2, vx, npg);
}